// Round 1
// 423.342 us; speedup vs baseline: 1.0306x; 1.0306x over previous
//
#include <hip/hip_runtime.h>
#include <hip/hip_bf16.h>

// Problem constants (B,L,D)=(4,2048,768), K=12, M=1, CK=4, H=64
#define B_       4
#define L_       2048
#define D_       768
#define K_       12
#define H_       64
#define CK_      4
#define DIM_MEM_ 768
#define DMK      780        // DIM_MEM + K
#define NT       (B_*L_)    // 8192 tokens
#define NSUM     1536       // 2*K*H  (summary width)
#define NACT     2304       // K*192  (y_act width)
#define NCHUNK   16
#define CHLEN    (L_/NCHUNK)  // 128
#define PSTRIDE  132

typedef __attribute__((ext_vector_type(8))) short          bf16x8;
typedef __attribute__((ext_vector_type(8))) unsigned short u16x8;
typedef __attribute__((ext_vector_type(4))) float          f32x4;

__device__ __forceinline__ ushort f2bf(float v) {
    __hip_bfloat16 h = __float2bfloat16(v);
    return *reinterpret_cast<ushort*>(&h);
}
// fast tanh via hw exp; safe for any x
__device__ __forceinline__ float tanh_fast(float x) {
    float t = __expf(-2.f * fabsf(x));
    float r = (1.f - t) / (1.f + t);
    return copysignf(r, x);
}

// ---------------------------------------------------------------------------
// Merged prep: transpose-cast jobs (32x32 LDS tiles) + x->bf16 cast.
// remap==1: interleaved val/gate layout for the fused spectral GEMM:
//   virtual col vc: grp=vc>>5, which=(vc>>4)&1, nn=grp*16+(vc&15)
//   orig col = colbase + (nn/192)*384 + which*192 + (nn%192)
// ---------------------------------------------------------------------------
struct PrepJobs {
    const float* W[6];
    ushort*      out[6];
    int ldw[6], Kd[6], colbase[6], remap[6], ntx[6];
    int start[7];
    const float* cast_in;
    ushort*      cast_out;
    int n4;
};

__global__ __launch_bounds__(256)
void prep_all(PrepJobs J)
{
    int blk = blockIdx.x;
    if (blk >= J.start[6]) {                       // cast job
        int i = (blk - J.start[6]) * 256 + threadIdx.x;
        if (i < J.n4) {
            float4 v = reinterpret_cast<const float4*>(J.cast_in)[i];
            ushort4 o;
            o.x = f2bf(v.x); o.y = f2bf(v.y); o.z = f2bf(v.z); o.w = f2bf(v.w);
            reinterpret_cast<ushort4*>(J.cast_out)[i] = o;
        }
        return;
    }
    int j = 0;
    while (blk >= J.start[j + 1]) ++j;
    int rel = blk - J.start[j];
    int ntx = J.ntx[j];
    int n0 = (rel % ntx) * 32, k0 = (rel / ntx) * 32;
    const float* W = J.W[j];
    int ldw = J.ldw[j], Kd = J.Kd[j], colbase = J.colbase[j], remap = J.remap[j];
    ushort* out = J.out[j];

    __shared__ float tile[32][33];
    int tx = threadIdx.x & 31, ty = threadIdx.x >> 5;
    int n = n0 + tx;
    int c;
    if (remap) {
        int grp = n >> 5, which = (n >> 4) & 1, nn = (grp << 4) + (n & 15);
        c = colbase + (nn / 192) * 384 + which * 192 + (nn % 192);
    } else {
        c = colbase + n;
    }
    #pragma unroll
    for (int r = 0; r < 4; ++r)
        tile[ty + r*8][tx] = W[(size_t)(k0 + ty + r*8) * ldw + c];
    __syncthreads();
    #pragma unroll
    for (int r = 0; r < 4; ++r)
        out[(size_t)(n0 + ty + r*8) * Kd + k0 + tx] = f2bf(tile[tx][ty + r*8]);
}

// ---------------------------------------------------------------------------
// bf16 MFMA GEMM: C[M,N] fp32 = A[M,K] * BT[Nr,K]^T, write guard col<N.
// 128x128 tile, BK=64, 4 waves each 64x64. PROVEN sync discipline only.
// ---------------------------------------------------------------------------
__global__ __launch_bounds__(256)
void gemm_bf16_mfma(const ushort* __restrict__ A, const ushort* __restrict__ BT,
                    float* __restrict__ C, int Kd, int N, int ldc)
{
    __shared__ ushort As[128*64];   // 16 KB
    __shared__ ushort Bs[128*64];   // 16 KB
    int tid = threadIdx.x, lane = tid & 63;
    int lr = lane & 15, quad = lane >> 4;
    int wave = tid >> 6;
    int wr = (wave >> 1) * 64, wc = (wave & 1) * 64;
    int m0 = blockIdx.y * 128, n0 = blockIdx.x * 128;

    f32x4 acc[4][4] = {};

    int srow = tid >> 3;                       // 0..31
    int tc   = tid & 7;                        // logical k-chunk (8B*2=16B)
    const ushort* gA = A  + (size_t)(m0 + srow) * Kd + tc * 8;
    const ushort* gB = BT + (size_t)(n0 + srow) * Kd + tc * 8;
    int woff = srow * 64 + ((tc ^ (srow & 7)) * 8);
    int rx = lr & 7;

    for (int k0 = 0; k0 < Kd; k0 += 64) {
        u16x8 a[4], b[4];
        #pragma unroll
        for (int p = 0; p < 4; ++p) {
            a[p] = *reinterpret_cast<const u16x8*>(gA + (size_t)(32*p) * Kd);
            b[p] = *reinterpret_cast<const u16x8*>(gB + (size_t)(32*p) * Kd);
        }
        gA += 64; gB += 64;
        __syncthreads();               // prev iteration's LDS reads complete
        #pragma unroll
        for (int p = 0; p < 4; ++p) {
            *reinterpret_cast<u16x8*>(As + woff + p*2048) = a[p];
            *reinterpret_cast<u16x8*>(Bs + woff + p*2048) = b[p];
        }
        __syncthreads();               // staging visible to all waves
        #pragma unroll
        for (int ks = 0; ks < 2; ++ks) {
            bf16x8 af[4], bf[4];
            #pragma unroll
            for (int i = 0; i < 4; ++i) {
                int ca = ((ks*4 + quad) ^ rx) * 8;
                af[i] = *reinterpret_cast<const bf16x8*>(As + (wr + i*16 + lr) * 64 + ca);
                bf[i] = *reinterpret_cast<const bf16x8*>(Bs + (wc + i*16 + lr) * 64 + ca);
            }
            #pragma unroll
            for (int i = 0; i < 4; ++i)
                #pragma unroll
                for (int j = 0; j < 4; ++j)
                    acc[i][j] = __builtin_amdgcn_mfma_f32_16x16x32_bf16(
                                    af[i], bf[j], acc[i][j], 0, 0, 0);
        }
    }

    #pragma unroll
    for (int i = 0; i < 4; ++i)
        #pragma unroll
        for (int j = 0; j < 4; ++j)
            #pragma unroll
            for (int r = 0; r < 4; ++r) {
                int row = m0 + wr + i*16 + quad*4 + r;      // m89-verified C/D map
                int col = n0 + wc + j*16 + lr;
                if (col < N)
                    C[(size_t)row * ldc + col] = acc[i][j][r];
            }
}

// ---------------------------------------------------------------------------
// Fused spectral+skip GEMM, 8-wave deep-pipelined (T3+T4+T5):
//   virtual C[8192, 4608] = [summary|x] @ [WsCat|WiCat]^T, val/gate columns
//   interleaved in 32-groups so each lane holds its (v,g) pair at epilogue.
// Tile 256(M) x 192(Nv), BK=64, 512 thr = 8 waves (4M x 2N), 64x96/wave.
// Grid 32x24 = 768 blocks = exactly 3 rounds of 256 CUs at 1 block/CU.
// Staging: global_load_lds width=16, linear LDS dest, PRE-SWIZZLED global
// source (chunk ^ (row&7), 16B granularity) + same swizzle on ds_read side.
// Schedule per K-tile (3 phases, 16 MFMA each):
//   P0: ds_read af(8)+bf01(4); issue B(g+1) [other buf]; bar; lgkm0; MFMA
//   P1: ds_read bf23(4);       issue A(g+2) part0 [own buf, af reads done]; ...
//   P2: ds_read bf45(4);       issue A(g+2) part1; vmcnt(4); bar; lgkm0; MFMA
// vmcnt(4) leaves exactly A(g+2) in flight; guarantees A(g+1),B(g+1) landed.
// Never drains vmcnt to 0 inside the loop.
// ---------------------------------------------------------------------------
#define G2NKT 36   // 24 k-tiles of summary (K=1536) + 12 of x (K=768)

#define GLOAD16(gp, dp) __builtin_amdgcn_global_load_lds( \
    (__attribute__((address_space(1))) const void*)(gp),  \
    (__attribute__((address_space(3))) void*)(dp), 16, 0, 0)

__device__ __forceinline__ void g2_stageA(ushort* lds_, int kt,
                                          const ushort* pAs, const ushort* pAx,
                                          int wave, int part)
{
    int ktc = kt > (G2NKT-1) ? (G2NKT-1) : kt;   // clamp src; dest parity uses kt
    const ushort* g; size_t kd;
    if (ktc < 24) { g = pAs + ktc*64;      kd = 1536; }
    else          { g = pAx + (ktc-24)*64; kd = 768;  }
    g += (size_t)(part * 128) * kd;
    ushort* d = lds_ + (kt & 1) * 16384 + part * 8192 + wave * 512;
    GLOAD16(g,           d);
    GLOAD16(g + 64*kd,   d + 4096);
}

__device__ __forceinline__ void g2_stageB(ushort* lds_, int kt,
                                          const ushort* pBs, const ushort* pBx,
                                          int wave)
{
    int ktc = kt > (G2NKT-1) ? (G2NKT-1) : kt;
    const ushort* g; size_t kd;
    if (ktc < 24) { g = pBs + ktc*64;      kd = 1536; }
    else          { g = pBx + (ktc-24)*64; kd = 768;  }
    ushort* d = lds_ + 32768 + (kt & 1) * 12288 + wave * 512;
    GLOAD16(g,           d);
    GLOAD16(g + 64*kd,   d + 4096);
    GLOAD16(g + 128*kd,  d + 8192);
}

__global__ __launch_bounds__(512, 2)
void gemm2_8ph(const ushort* __restrict__ Sm, const ushort* __restrict__ Xb,
               const ushort* __restrict__ WsC, const ushort* __restrict__ WiC,
               ushort* __restrict__ yact)
{
    // LDS (ushort units): A bufs @0 and @16384 (256x64 each);
    //                     B bufs @32768 and @45056 (192x64 each). 112 KiB.
    __shared__ ushort lds[57344];
    const int tid  = threadIdx.x;
    const int lane = tid & 63, wave = tid >> 6;
    const int lr = lane & 15, quad = lane >> 4, rx = lr & 7;
    const int wr = (wave >> 1) * 64;     // 0,64,128,192
    const int wc = (wave & 1) * 96;      // 0,96
    const int m0 = blockIdx.y * 256, n0 = blockIdx.x * 192;

    // staging source pointers (pre-swizzled chunk)
    const int sr = tid >> 3;             // 0..63
    const int sc = (tid & 7) ^ (sr & 7); // logical chunk fetched for linear slot
    const ushort* pAs = Sm  + (size_t)(m0 + sr) * 1536 + sc * 8;
    const ushort* pAx = Xb  + (size_t)(m0 + sr) * 768  + sc * 8;
    const ushort* pBs = WsC + (size_t)(n0 + sr) * 1536 + sc * 8;
    const ushort* pBx = WiC + (size_t)(n0 + sr) * 768  + sc * 8;

    f32x4 acc[4][6] = {};
    bf16x8 af[4][2];
    const int ca0 = (quad ^ rx) * 8;
    const int ca1 = ((4 + quad) ^ rx) * 8;

    // prologue: A(0), B(0), A(1) = 11 loads; vmcnt(4) leaves A(1) in flight
    g2_stageA(lds, 0, pAs, pAx, wave, 0);
    g2_stageA(lds, 0, pAs, pAx, wave, 1);
    g2_stageB(lds, 0, pBs, pBx, wave);
    g2_stageA(lds, 1, pAs, pAx, wave, 0);
    g2_stageA(lds, 1, pAs, pAx, wave, 1);
    asm volatile("s_waitcnt vmcnt(4)" ::: "memory");
    __builtin_amdgcn_s_barrier();

    #pragma unroll 1
    for (int g = 0; g < G2NKT; ++g) {
        const ushort* Ab = lds + (g & 1) * 16384;
        const ushort* Bb = lds + 32768 + (g & 1) * 12288;

        // ---------------- phase 0 : j=0,1 ----------------
        {
            #pragma unroll
            for (int i = 0; i < 4; ++i) {
                const ushort* p = Ab + (wr + i*16 + lr) * 64;
                af[i][0] = *reinterpret_cast<const bf16x8*>(p + ca0);
                af[i][1] = *reinterpret_cast<const bf16x8*>(p + ca1);
            }
            bf16x8 bfr[2][2];
            #pragma unroll
            for (int j = 0; j < 2; ++j) {
                const ushort* p = Bb + (wc + j*16 + lr) * 64;
                bfr[j][0] = *reinterpret_cast<const bf16x8*>(p + ca0);
                bfr[j][1] = *reinterpret_cast<const bf16x8*>(p + ca1);
            }
            g2_stageB(lds, g + 1, pBs, pBx, wave);  // other B buffer: safe
            __builtin_amdgcn_s_barrier();
            asm volatile("s_waitcnt lgkmcnt(0)" ::: "memory");
            __builtin_amdgcn_sched_barrier(0);
            __builtin_amdgcn_s_setprio(1);
            #pragma unroll
            for (int ks = 0; ks < 2; ++ks)
                #pragma unroll
                for (int i = 0; i < 4; ++i)
                    #pragma unroll
                    for (int j = 0; j < 2; ++j)
                        acc[i][j] = __builtin_amdgcn_mfma_f32_16x16x32_bf16(
                                        af[i][ks], bfr[j][ks], acc[i][j], 0, 0, 0);
            __builtin_amdgcn_s_setprio(0);
            __builtin_amdgcn_s_barrier();
        }
        // ---------------- phase 1 : j=2,3 ----------------
        {
            bf16x8 bfr[2][2];
            #pragma unroll
            for (int j = 0; j < 2; ++j) {
                const ushort* p = Bb + (wc + (2 + j)*16 + lr) * 64;
                bfr[j][0] = *reinterpret_cast<const bf16x8*>(p + ca0);
                bfr[j][1] = *reinterpret_cast<const bf16x8*>(p + ca1);
            }
            // own A buffer, but all af reads completed before P0's end barrier
            g2_stageA(lds, g + 2, pAs, pAx, wave, 0);
            __builtin_amdgcn_s_barrier();
            asm volatile("s_waitcnt lgkmcnt(0)" ::: "memory");
            __builtin_amdgcn_sched_barrier(0);
            __builtin_amdgcn_s_setprio(1);
            #pragma unroll
            for (int ks = 0; ks < 2; ++ks)
                #pragma unroll
                for (int i = 0; i < 4; ++i)
                    #pragma unroll
                    for (int j = 0; j < 2; ++j)
                        acc[i][2 + j] = __builtin_amdgcn_mfma_f32_16x16x32_bf16(
                                        af[i][ks], bfr[j][ks], acc[i][2 + j], 0, 0, 0);
            __builtin_amdgcn_s_setprio(0);
            __builtin_amdgcn_s_barrier();
        }
        // ---------------- phase 2 : j=4,5 ----------------
        {
            bf16x8 bfr[2][2];
            #pragma unroll
            for (int j = 0; j < 2; ++j) {
                const ushort* p = Bb + (wc + (4 + j)*16 + lr) * 64;
                bfr[j][0] = *reinterpret_cast<const bf16x8*>(p + ca0);
                bfr[j][1] = *reinterpret_cast<const bf16x8*>(p + ca1);
            }
            g2_stageA(lds, g + 2, pAs, pAx, wave, 1);
            // counted wait: drains A(g+1),B(g+1); leaves A(g+2) in flight
            asm volatile("s_waitcnt vmcnt(4)" ::: "memory");
            __builtin_amdgcn_s_barrier();
            asm volatile("s_waitcnt lgkmcnt(0)" ::: "memory");
            __builtin_amdgcn_sched_barrier(0);
            __builtin_amdgcn_s_setprio(1);
            #pragma unroll
            for (int ks = 0; ks < 2; ++ks)
                #pragma unroll
                for (int i = 0; i < 4; ++i)
                    #pragma unroll
                    for (int j = 0; j < 2; ++j)
                        acc[i][4 + j] = __builtin_amdgcn_mfma_f32_16x16x32_bf16(
                                        af[i][ks], bfr[j][ks], acc[i][4 + j], 0, 0, 0);
            __builtin_amdgcn_s_setprio(0);
            __builtin_amdgcn_s_barrier();
        }
    }
    asm volatile("s_waitcnt vmcnt(0)" ::: "memory");  // drain tail garbage stages

    // epilogue: lane-local (val,gate) pairs -> gated SiLU -> bf16
    const int vg0 = (n0 + wc) >> 5;
    #pragma unroll
    for (int i = 0; i < 4; ++i)
        #pragma unroll
        for (int p = 0; p < 3; ++p)
            #pragma unroll
            for (int r = 0; r < 4; ++r) {
                int row = m0 + wr + i*16 + quad*4 + r;      // m89-verified C/D map
                int col = (vg0 + p)*16 + lr;
                float v  = acc[i][2*p][r];
                float gt = acc[i][2*p + 1][r];
                float y = v * (gt / (1.f + __expf(-gt)));
                yact[(size_t)row * NACT + col] = f2bf(y);
            }
}

// ---------------------------------------------------------------------------
// Token-local: conv(CK=4)+SiLU+RMSNorm(H)+phase -> pw, re, im
// ---------------------------------------------------------------------------
__global__ __launch_bounds__(256)
void token_kernel(const float* __restrict__ zmem, const float* __restrict__ conv_w,
                  const float* __restrict__ rms_scale, const float* __restrict__ theta_raw,
                  const float* __restrict__ dslopes, const float* __restrict__ sscale,
                  const float* __restrict__ tscale,
                  float* __restrict__ pw, float* __restrict__ re, float* __restrict__ im)
{
    int t = blockIdx.x;
    int b = t >> 11;
    int l = t & (L_ - 1);
    int tid = threadIdx.x;
    int h = tid & 63, kg = tid >> 6;

    __shared__ float s_pw[K_];

    if (tid < K_) {
        float acc = 0.f;
        #pragma unroll
        for (int j = 0; j < CK_; ++j) {
            int ll = l - (CK_ - 1) + j;
            if (ll >= 0)
                acc += zmem[(size_t)(b*L_ + ll)*DMK + DIM_MEM_ + tid]
                     * conv_w[j*DMK + DIM_MEM_ + tid];
        }
        float s  = acc / (1.f + expf(-acc));
        float lp = sscale[tid] * s;
        lp = fminf(10.f, fmaxf(-10.f, lp));
        float slope = log1pf(expf(dslopes[tid]));
        s_pw[tid] = expf(lp - slope * (float)(L_ - 1 - l));
    }

    float kv[3];
    #pragma unroll
    for (int q = 0; q < 3; ++q) {
        int kk = kg + q*4;
        int c = kk*H_ + h;
        float acc = 0.f;
        #pragma unroll
        for (int j = 0; j < CK_; ++j) {
            int ll = l - (CK_ - 1) + j;
            if (ll >= 0)
                acc += zmem[(size_t)(b*L_ + ll)*DMK + c] * conv_w[j*DMK + c];
        }
        kv[q] = acc / (1.f + __expf(-acc));          // silu (hw exp)
    }
    __syncthreads();

    #pragma unroll
    for (int q = 0; q < 3; ++q) {
        int kk = kg + q*4;
        float v = kv[q];
        float ss = v * v;
        #pragma unroll
        for (int off = 32; off > 0; off >>= 1)
            ss += __shfl_xor(ss, off, 64);
        float kn = v * rsqrtf(ss * (1.f/64.f) + 1e-6f) * rms_scale[h];
        float th = 0.001f + 2.999f * (1.f / (1.f + __expf(-theta_raw[kk*H_ + h])));
        float phi = tanh_fast(kn * tscale[kk]) * th;
        float kvw = kn * s_pw[kk];
        re[(size_t)t*(K_*H_) + kk*H_ + h] = kvw * __cosf(phi);
        im[(size_t)t*(K_*H_) + kk*H_ + h] = kvw * __sinf(phi);
    }
    if (tid < K_) pw[(size_t)t*K_ + tid] = s_pw[tid];
}

// ---------------------------------------------------------------------------
// Chunked scan pass 1
// ---------------------------------------------------------------------------
__global__ __launch_bounds__(128)
void scan_sums(const float* __restrict__ pw, const float* __restrict__ re,
               const float* __restrict__ im, float* __restrict__ part)
{
    int blk = blockIdx.x;
    int chunk = blk & (NCHUNK - 1);
    int bk = blk >> 4;
    int k = bk % K_;
    int b = bk / K_;
    int tid = threadIdx.x;
    int h = tid & 63;
    const float* __restrict__ src = (tid >> 6) ? im : re;
    int l0 = chunk * CHLEN;

    size_t base  = ((size_t)(b*L_ + l0))*(K_*H_) + k*H_ + h;
    size_t dbase = ((size_t)(b*L_ + l0))*K_ + k;
    float s = 0.f, ds = 0.f;
    for (int i0 = 0; i0 < CHLEN; i0 += 8) {
        float v[8], d[8];
        #pragma unroll
        for (int j = 0; j < 8; ++j) {
            v[j] = src[base + (size_t)(i0 + j)*(K_*H_)];
            d[j] = pw [dbase + (size_t)(i0 + j)*K_];
        }
        #pragma unroll
        for (int j = 0; j < 8; ++j) { s += v[j]; ds += d[j]; }
    }
    size_t pb = ((size_t)bk * NCHUNK + chunk) * PSTRIDE;
    part[pb + tid] = s;
    if (tid == 0) part[pb + 128] = ds;
}

// ---------------------------------------------------------------------------
// Chunked scan pass 2: emit summary directly as bf16.
// ---------------------------------------------------------------------------
__global__ __launch_bounds__(128)
void scan_final(const float* __restrict__ pw, const float* __restrict__ re,
                const float* __restrict__ im, const float* __restrict__ part,
                ushort* __restrict__ summary)
{
    int blk = blockIdx.x;
    int chunk = blk & (NCHUNK - 1);
    int bk = blk >> 4;
    int k = bk % K_;
    int b = bk / K_;
    int tid = threadIdx.x;
    int h = tid & 63;
    int pi = tid >> 6;
    const float* __restrict__ src = pi ? im : re;
    int l0 = chunk * CHLEN;

    float acc = 0.f, dacc = 0.f;
    size_t pb0 = (size_t)bk * NCHUNK * PSTRIDE;
    for (int cn = 0; cn < chunk; ++cn) {
        acc  += part[pb0 + (size_t)cn*PSTRIDE + tid];
        dacc += part[pb0 + (size_t)cn*PSTRIDE + 128];
    }

    size_t base  = ((size_t)(b*L_ + l0))*(K_*H_) + k*H_ + h;
    size_t dbase = ((size_t)(b*L_ + l0))*K_ + k;
    int outch = 2*(k*H_ + h) + pi;
    for (int i0 = 0; i0 < CHLEN; i0 += 8) {
        float v[8], d[8];
        #pragma unroll
        for (int j = 0; j < 8; ++j) {
            v[j] = src[base + (size_t)(i0 + j)*(K_*H_)];
            d[j] = pw [dbase + (size_t)(i0 + j)*K_];
        }
        #pragma unroll
        for (int j = 0; j < 8; ++j) {
            acc += v[j]; dacc += d[j];
            float inv = 1.f / fmaxf(dacc, 1e-4f);
            summary[((size_t)(b*L_ + l0 + i0 + j))*NSUM + outch] = f2bf(acc * inv);
        }
    }
}

// ---------------------------------------------------------------------------
extern "C" void kernel_launch(void* const* d_in, const int* in_sizes, int n_in,
                              void* d_out, int out_size, void* d_ws, size_t ws_size,
                              hipStream_t stream)
{
    const float* x         = (const float*)d_in[0];
    const float* W_in      = (const float*)d_in[1];
    const float* conv_w    = (const float*)d_in[2];
    const float* rms_scale = (const float*)d_in[3];
    const float* theta_raw = (const float*)d_in[4];
    const float* dslopes   = (const float*)d_in[5];
    const float* sscale    = (const float*)d_in[6];
    const float* tscale    = (const float*)d_in[7];
    const float* W_sw      = (const float*)d_in[8];
    const float* W_out     = (const float*)d_in[9];
    float* out = (float*)d_out;
    char* ws   = (char*)d_ws;

    // Workspace (byte offsets, all 256-aligned). Peak ~115.4 MB (< proven 127).
    float*  zmem    = (float*) (ws + 0);           // NT*780 f32   = 25,559,040 B
    ushort* summary = (ushort*)(ws + 0);           // alias (zmem dead): 25,165,824 B
    float*  pw      = (float*) (ws + 25559040);    //   393,216 B
    float*  re      = (float*) (ws + 25952256);    // 25,165,824 B
    float*  im      = (float*) (ws + 51118080);    // 25,165,824 B
    ushort* yact    = (ushort*)(ws + 25952256);    // alias re+im (dead): 37,748,736 B
    float*  part    = (float*) (ws + 76283904);    //   405,504 B
    ushort* xb      = (ushort*)(ws + 76689408);    // 12,582,912 B
    ushort* WiCat   = (ushort*)(ws + 89272320);    //  7,077,888 B  [4608][768]  val/gate interleaved
    ushort* WsCat   = (ushort*)(ws + 96350208);    // 14,155,776 B  [4608][1536] val/gate interleaved
    ushort* WoT     = (ushort*)(ws + 110505984);   //  3,538,944 B  [768][2304]
    ushort* WimT    = (ushort*)(ws + 114044928);   //  1,376,256 B  [896][768] (pad)

    // ---- merged prep job table ----
    PrepJobs J{};
    J.W[0]=W_in;  J.out[0]=WiCat; J.ldw[0]=5388; J.Kd[0]=768;  J.colbase[0]=780; J.remap[0]=1; J.ntx[0]=144;
    J.W[1]=W_sw;  J.out[1]=WsCat; J.ldw[1]=4608; J.Kd[1]=1536; J.colbase[1]=0;   J.remap[1]=1; J.ntx[1]=144;
    J.W[2]=W_out; J.out[2]=WoT;   J.ldw[2]=768;  J.Kd[2]=2304; J.colbase[2]=0;   J.remap[2]=0; J.ntx[2]=24;
    J.W[3]=W_in;  J.out[3]=WimT;  J.ldw[3]=5388; J.Kd[3]=768;  J.colbase[3]=0;   J.remap[3]=0; J.ntx[3]=28;
    int tiles[4] = {144*24, 144*48, 24*72, 28*24};
    J.start[0] = 0;
    for (int j = 0; j < 4; ++j) J.start[j+1] = J.start[j] + tiles[j];
    J.start[5] = J.start[4];
    J.start[6] = J.start[4];
    J.cast_in = x; J.cast_out = xb; J.n4 = NT*D_/4;
    int nblk = J.start[6] + (J.n4 + 255)/256;

    dim3 blk(256);
    // 0) all preps in one launch
    prep_all<<<dim3(nblk), blk, 0, stream>>>(J);
    // 1) z_mem = x @ W_in[:, :780]  (bf16 MFMA, col-guarded at 780)
    gemm_bf16_mfma<<<dim3(7, 64), blk, 0, stream>>>(xb, WimT, zmem, 768, 780, 780);
    // 2) conv + silu + rmsnorm + phase
    token_kernel<<<dim3(NT), blk, 0, stream>>>(zmem, conv_w, rms_scale, theta_raw,
                                               dslopes, sscale, tscale, pw, re, im);
    // 3) chunked cumsum -> summary (bf16)
    scan_sums <<<dim3(B_*K_*NCHUNK), dim3(128), 0, stream>>>(pw, re, im, part);
    scan_final<<<dim3(B_*K_*NCHUNK), dim3(128), 0, stream>>>(pw, re, im, part, summary);
    // 4) fused spectral+skip deep-pipelined GEMM with gated-SiLU epilogue -> yact
    gemm2_8ph<<<dim3(24, 32), dim3(512), 0, stream>>>(summary, xb, WsCat, WiCat, yact);
    // 5) out = yact @ W_out  (MFMA)
    gemm_bf16_mfma<<<dim3(6, 64), blk, 0, stream>>>(yact, WoT, out, 2304, 768, 768);
}

// Round 2
// 409.712 us; speedup vs baseline: 1.0649x; 1.0333x over previous
//
#include <hip/hip_runtime.h>
#include <hip/hip_bf16.h>

// Problem constants (B,L,D)=(4,2048,768), K=12, M=1, CK=4, H=64
#define B_       4
#define L_       2048
#define D_       768
#define K_       12
#define H_       64
#define CK_      4
#define DIM_MEM_ 768
#define DMK      780        // DIM_MEM + K
#define NT       (B_*L_)    // 8192 tokens
#define NSUM     1536       // 2*K*H  (summary width)
#define NACT     2304       // K*192  (y_act width)
#define NCHUNK   16
#define CHLEN    (L_/NCHUNK)  // 128
#define PSTRIDE  132

typedef __attribute__((ext_vector_type(8))) short          bf16x8;
typedef __attribute__((ext_vector_type(8))) unsigned short u16x8;
typedef __attribute__((ext_vector_type(4))) float          f32x4;

__device__ __forceinline__ ushort f2bf(float v) {
    __hip_bfloat16 h = __float2bfloat16(v);
    return *reinterpret_cast<ushort*>(&h);
}
// fast tanh via hw exp; safe for any x
__device__ __forceinline__ float tanh_fast(float x) {
    float t = __expf(-2.f * fabsf(x));
    float r = (1.f - t) / (1.f + t);
    return copysignf(r, x);
}

// ---------------------------------------------------------------------------
// Merged prep: transpose-cast jobs (32x32 LDS tiles) + x->bf16 cast.
// remap==1: interleaved val/gate layout for the fused spectral GEMM:
//   virtual col vc: grp=vc>>5, which=(vc>>4)&1, nn=grp*16+(vc&15)
//   orig col = colbase + (nn/192)*384 + which*192 + (nn%192)
// ---------------------------------------------------------------------------
struct PrepJobs {
    const float* W[6];
    ushort*      out[6];
    int ldw[6], Kd[6], colbase[6], remap[6], ntx[6];
    int start[7];
    const float* cast_in;
    ushort*      cast_out;
    int n4;
};

__global__ __launch_bounds__(256)
void prep_all(PrepJobs J)
{
    int blk = blockIdx.x;
    if (blk >= J.start[6]) {                       // cast job
        int i = (blk - J.start[6]) * 256 + threadIdx.x;
        if (i < J.n4) {
            float4 v = reinterpret_cast<const float4*>(J.cast_in)[i];
            ushort4 o;
            o.x = f2bf(v.x); o.y = f2bf(v.y); o.z = f2bf(v.z); o.w = f2bf(v.w);
            reinterpret_cast<ushort4*>(J.cast_out)[i] = o;
        }
        return;
    }
    int j = 0;
    while (blk >= J.start[j + 1]) ++j;
    int rel = blk - J.start[j];
    int ntx = J.ntx[j];
    int n0 = (rel % ntx) * 32, k0 = (rel / ntx) * 32;
    const float* W = J.W[j];
    int ldw = J.ldw[j], Kd = J.Kd[j], colbase = J.colbase[j], remap = J.remap[j];
    ushort* out = J.out[j];

    __shared__ float tile[32][33];
    int tx = threadIdx.x & 31, ty = threadIdx.x >> 5;
    int n = n0 + tx;
    int c;
    if (remap) {
        int grp = n >> 5, which = (n >> 4) & 1, nn = (grp << 4) + (n & 15);
        c = colbase + (nn / 192) * 384 + which * 192 + (nn % 192);
    } else {
        c = colbase + n;
    }
    #pragma unroll
    for (int r = 0; r < 4; ++r)
        tile[ty + r*8][tx] = W[(size_t)(k0 + ty + r*8) * ldw + c];
    __syncthreads();
    #pragma unroll
    for (int r = 0; r < 4; ++r)
        out[(size_t)(n0 + ty + r*8) * Kd + k0 + tx] = f2bf(tile[tx][ty + r*8]);
}

// ---------------------------------------------------------------------------
// bf16 MFMA GEMM: C[M,N] fp32 = A[M,K] * BT[Nr,K]^T, write guard col<N.
// 128x128 tile, BK=64, 4 waves each 64x64. PROVEN sync discipline only.
// ---------------------------------------------------------------------------
__global__ __launch_bounds__(256)
void gemm_bf16_mfma(const ushort* __restrict__ A, const ushort* __restrict__ BT,
                    float* __restrict__ C, int Kd, int N, int ldc)
{
    __shared__ ushort As[128*64];   // 16 KB
    __shared__ ushort Bs[128*64];   // 16 KB
    int tid = threadIdx.x, lane = tid & 63;
    int lr = lane & 15, quad = lane >> 4;
    int wave = tid >> 6;
    int wr = (wave >> 1) * 64, wc = (wave & 1) * 64;
    int m0 = blockIdx.y * 128, n0 = blockIdx.x * 128;

    f32x4 acc[4][4] = {};

    int srow = tid >> 3;                       // 0..31
    int tc   = tid & 7;                        // logical k-chunk (8B*2=16B)
    const ushort* gA = A  + (size_t)(m0 + srow) * Kd + tc * 8;
    const ushort* gB = BT + (size_t)(n0 + srow) * Kd + tc * 8;
    int woff = srow * 64 + ((tc ^ (srow & 7)) * 8);
    int rx = lr & 7;

    for (int k0 = 0; k0 < Kd; k0 += 64) {
        u16x8 a[4], b[4];
        #pragma unroll
        for (int p = 0; p < 4; ++p) {
            a[p] = *reinterpret_cast<const u16x8*>(gA + (size_t)(32*p) * Kd);
            b[p] = *reinterpret_cast<const u16x8*>(gB + (size_t)(32*p) * Kd);
        }
        gA += 64; gB += 64;
        __syncthreads();               // prev iteration's LDS reads complete
        #pragma unroll
        for (int p = 0; p < 4; ++p) {
            *reinterpret_cast<u16x8*>(As + woff + p*2048) = a[p];
            *reinterpret_cast<u16x8*>(Bs + woff + p*2048) = b[p];
        }
        __syncthreads();               // staging visible to all waves
        #pragma unroll
        for (int ks = 0; ks < 2; ++ks) {
            bf16x8 af[4], bf[4];
            #pragma unroll
            for (int i = 0; i < 4; ++i) {
                int ca = ((ks*4 + quad) ^ rx) * 8;
                af[i] = *reinterpret_cast<const bf16x8*>(As + (wr + i*16 + lr) * 64 + ca);
                bf[i] = *reinterpret_cast<const bf16x8*>(Bs + (wc + i*16 + lr) * 64 + ca);
            }
            #pragma unroll
            for (int i = 0; i < 4; ++i)
                #pragma unroll
                for (int j = 0; j < 4; ++j)
                    acc[i][j] = __builtin_amdgcn_mfma_f32_16x16x32_bf16(
                                    af[i], bf[j], acc[i][j], 0, 0, 0);
        }
    }

    #pragma unroll
    for (int i = 0; i < 4; ++i)
        #pragma unroll
        for (int j = 0; j < 4; ++j)
            #pragma unroll
            for (int r = 0; r < 4; ++r) {
                int row = m0 + wr + i*16 + quad*4 + r;      // m89-verified C/D map
                int col = n0 + wc + j*16 + lr;
                if (col < N)
                    C[(size_t)row * ldc + col] = acc[i][j][r];
            }
}

// ---------------------------------------------------------------------------
// Fused spectral+skip GEMM, pipelined + 2 blocks/CU:
//   virtual C[8192, 4608] = [summary|x] @ [WsCat|WiCat]^T, val/gate columns
//   interleaved in 32-groups so each lane holds its (v,g) pair at epilogue.
// Tile 128(M) x 192(Nv), BK=64, 256 thr = 4 waves (2M x 2N), 64x96/wave.
// LDS 80 KiB -> exactly 2 blocks/CU (163840 B): each SIMD carries 2 waves
// from INDEPENDENT blocks, so one block's barrier/lgkm stalls overlap the
// other's MFMA bursts (the overlap the 8-wave lockstep version lacked).
// Grid 24x64 = 1536 blocks = 3 clean rounds of 512 co-resident.
// Schedule per K-tile (3 phases, 16 MFMA each), counted vmcnt, never 0:
//   P0: ds_read af(8)+bf01(4); issue B(g+1) [6 ld, other buf]; bar; lgkm0; MFMA
//   P1: ds_read bf23(4);       issue A(g+2) part0 [2 ld, own buf: af done]; ...
//   P2: ds_read bf45(4);       issue A(g+2) part1 [2 ld]; vmcnt(4); bar; ...
// Queue at P2's vmcnt: [A(g+1)x4, B(g+1)x6, A(g+2)x4] -> drains A/B(g+1),
// leaves A(g+2) in flight.
// ---------------------------------------------------------------------------
#define G2NKT 36   // 24 k-tiles of summary (K=1536) + 12 of x (K=768)

#define GLOAD16(gp, dp) __builtin_amdgcn_global_load_lds( \
    (__attribute__((address_space(1))) const void*)(gp),  \
    (__attribute__((address_space(3))) void*)(dp), 16, 0, 0)

__device__ __forceinline__ void g2_stageA(ushort* lds_, int kt,
                                          const ushort* pAs, const ushort* pAx,
                                          int wave, int part)
{
    int ktc = kt > (G2NKT-1) ? (G2NKT-1) : kt;   // clamp src; dest parity uses kt
    const ushort* g; size_t kd;
    if (ktc < 24) { g = pAs + ktc*64;      kd = 1536; }
    else          { g = pAx + (ktc-24)*64; kd = 768;  }
    g += (size_t)(part * 64) * kd;               // rows part*64 .. part*64+63
    ushort* d = lds_ + (kt & 1) * 8192 + part * 4096 + wave * 512;
    GLOAD16(g,           d);
    GLOAD16(g + 32*kd,   d + 2048);
}

__device__ __forceinline__ void g2_stageB(ushort* lds_, int kt,
                                          const ushort* pBs, const ushort* pBx,
                                          int wave)
{
    int ktc = kt > (G2NKT-1) ? (G2NKT-1) : kt;
    const ushort* g; size_t kd;
    if (ktc < 24) { g = pBs + ktc*64;      kd = 1536; }
    else          { g = pBx + (ktc-24)*64; kd = 768;  }
    ushort* d = lds_ + 16384 + (kt & 1) * 12288 + wave * 512;
    #pragma unroll
    for (int s = 0; s < 6; ++s)
        GLOAD16(g + (size_t)(32*s)*kd, d + 2048*s);
}

__global__ __launch_bounds__(256, 2)
void gemm2_2blk(const ushort* __restrict__ Sm, const ushort* __restrict__ Xb,
                const ushort* __restrict__ WsC, const ushort* __restrict__ WiC,
                ushort* __restrict__ yact)
{
    // LDS (ushort units): A bufs @0 and @8192 (128x64 each);
    //                     B bufs @16384 and @28672 (192x64 each). 80 KiB.
    __shared__ ushort lds[40960];
    const int tid  = threadIdx.x;
    const int lane = tid & 63, wave = tid >> 6;      // wave 0..3
    const int lr = lane & 15, quad = lane >> 4, rx = lr & 7;
    const int wr = (wave >> 1) * 64;     // 0,64
    const int wc = (wave & 1) * 96;      // 0,96
    const int m0 = blockIdx.y * 128, n0 = blockIdx.x * 192;

    // staging source pointers (pre-swizzled chunk): LDS[row][c] holds global
    // chunk c^(row&7); reader XORs the same way.
    const int sr = tid >> 3;             // 0..31
    const int sc = (tid & 7) ^ (sr & 7);
    const ushort* pAs = Sm  + (size_t)(m0 + sr) * 1536 + sc * 8;
    const ushort* pAx = Xb  + (size_t)(m0 + sr) * 768  + sc * 8;
    const ushort* pBs = WsC + (size_t)(n0 + sr) * 1536 + sc * 8;
    const ushort* pBx = WiC + (size_t)(n0 + sr) * 768  + sc * 8;

    f32x4 acc[4][6] = {};
    bf16x8 af[4][2];
    const int ca0 = (quad ^ rx) * 8;
    const int ca1 = ((4 + quad) ^ rx) * 8;

    // prologue: A(0) 4 + B(0) 6 + A(1) 4 = 14 loads; vmcnt(4) leaves A(1)
    g2_stageA(lds, 0, pAs, pAx, wave, 0);
    g2_stageA(lds, 0, pAs, pAx, wave, 1);
    g2_stageB(lds, 0, pBs, pBx, wave);
    g2_stageA(lds, 1, pAs, pAx, wave, 0);
    g2_stageA(lds, 1, pAs, pAx, wave, 1);
    asm volatile("s_waitcnt vmcnt(4)" ::: "memory");
    __builtin_amdgcn_s_barrier();

    #pragma unroll 1
    for (int g = 0; g < G2NKT; ++g) {
        const ushort* Ab = lds + (g & 1) * 8192;
        const ushort* Bb = lds + 16384 + (g & 1) * 12288;

        // ---------------- phase 0 : j=0,1 ----------------
        {
            #pragma unroll
            for (int i = 0; i < 4; ++i) {
                const ushort* p = Ab + (wr + i*16 + lr) * 64;
                af[i][0] = *reinterpret_cast<const bf16x8*>(p + ca0);
                af[i][1] = *reinterpret_cast<const bf16x8*>(p + ca1);
            }
            bf16x8 bfr[2][2];
            #pragma unroll
            for (int j = 0; j < 2; ++j) {
                const ushort* p = Bb + (wc + j*16 + lr) * 64;
                bfr[j][0] = *reinterpret_cast<const bf16x8*>(p + ca0);
                bfr[j][1] = *reinterpret_cast<const bf16x8*>(p + ca1);
            }
            g2_stageB(lds, g + 1, pBs, pBx, wave);  // other B buffer: safe
            __builtin_amdgcn_s_barrier();
            asm volatile("s_waitcnt lgkmcnt(0)" ::: "memory");
            __builtin_amdgcn_sched_barrier(0);
            __builtin_amdgcn_s_setprio(1);
            #pragma unroll
            for (int ks = 0; ks < 2; ++ks)
                #pragma unroll
                for (int i = 0; i < 4; ++i)
                    #pragma unroll
                    for (int j = 0; j < 2; ++j)
                        acc[i][j] = __builtin_amdgcn_mfma_f32_16x16x32_bf16(
                                        af[i][ks], bfr[j][ks], acc[i][j], 0, 0, 0);
            __builtin_amdgcn_s_setprio(0);
            __builtin_amdgcn_s_barrier();
        }
        // ---------------- phase 1 : j=2,3 ----------------
        {
            bf16x8 bfr[2][2];
            #pragma unroll
            for (int j = 0; j < 2; ++j) {
                const ushort* p = Bb + (wc + (2 + j)*16 + lr) * 64;
                bfr[j][0] = *reinterpret_cast<const bf16x8*>(p + ca0);
                bfr[j][1] = *reinterpret_cast<const bf16x8*>(p + ca1);
            }
            // own A buffer, but all af reads completed before P0's end barrier
            g2_stageA(lds, g + 2, pAs, pAx, wave, 0);
            __builtin_amdgcn_s_barrier();
            asm volatile("s_waitcnt lgkmcnt(0)" ::: "memory");
            __builtin_amdgcn_sched_barrier(0);
            __builtin_amdgcn_s_setprio(1);
            #pragma unroll
            for (int ks = 0; ks < 2; ++ks)
                #pragma unroll
                for (int i = 0; i < 4; ++i)
                    #pragma unroll
                    for (int j = 0; j < 2; ++j)
                        acc[i][2 + j] = __builtin_amdgcn_mfma_f32_16x16x32_bf16(
                                        af[i][ks], bfr[j][ks], acc[i][2 + j], 0, 0, 0);
            __builtin_amdgcn_s_setprio(0);
            __builtin_amdgcn_s_barrier();
        }
        // ---------------- phase 2 : j=4,5 ----------------
        {
            bf16x8 bfr[2][2];
            #pragma unroll
            for (int j = 0; j < 2; ++j) {
                const ushort* p = Bb + (wc + (4 + j)*16 + lr) * 64;
                bfr[j][0] = *reinterpret_cast<const bf16x8*>(p + ca0);
                bfr[j][1] = *reinterpret_cast<const bf16x8*>(p + ca1);
            }
            g2_stageA(lds, g + 2, pAs, pAx, wave, 1);
            // counted wait: drains A(g+1),B(g+1); leaves A(g+2) in flight
            asm volatile("s_waitcnt vmcnt(4)" ::: "memory");
            __builtin_amdgcn_s_barrier();
            asm volatile("s_waitcnt lgkmcnt(0)" ::: "memory");
            __builtin_amdgcn_sched_barrier(0);
            __builtin_amdgcn_s_setprio(1);
            #pragma unroll
            for (int ks = 0; ks < 2; ++ks)
                #pragma unroll
                for (int i = 0; i < 4; ++i)
                    #pragma unroll
                    for (int j = 0; j < 2; ++j)
                        acc[i][4 + j] = __builtin_amdgcn_mfma_f32_16x16x32_bf16(
                                        af[i][ks], bfr[j][ks], acc[i][4 + j], 0, 0, 0);
            __builtin_amdgcn_s_setprio(0);
            __builtin_amdgcn_s_barrier();
        }
    }
    asm volatile("s_waitcnt vmcnt(0)" ::: "memory");  // drain tail garbage stages

    // epilogue: lane-local (val,gate) pairs -> gated SiLU -> bf16
    const int vg0 = (n0 + wc) >> 5;
    #pragma unroll
    for (int i = 0; i < 4; ++i)
        #pragma unroll
        for (int p = 0; p < 3; ++p)
            #pragma unroll
            for (int r = 0; r < 4; ++r) {
                int row = m0 + wr + i*16 + quad*4 + r;      // m89-verified C/D map
                int col = (vg0 + p)*16 + lr;
                float v  = acc[i][2*p][r];
                float gt = acc[i][2*p + 1][r];
                float y = v * (gt / (1.f + __expf(-gt)));
                yact[(size_t)row * NACT + col] = f2bf(y);
            }
}

// ---------------------------------------------------------------------------
// Token-local: conv(CK=4)+SiLU+RMSNorm(H)+phase -> pw, re, im
// ---------------------------------------------------------------------------
__global__ __launch_bounds__(256)
void token_kernel(const float* __restrict__ zmem, const float* __restrict__ conv_w,
                  const float* __restrict__ rms_scale, const float* __restrict__ theta_raw,
                  const float* __restrict__ dslopes, const float* __restrict__ sscale,
                  const float* __restrict__ tscale,
                  float* __restrict__ pw, float* __restrict__ re, float* __restrict__ im)
{
    int t = blockIdx.x;
    int b = t >> 11;
    int l = t & (L_ - 1);
    int tid = threadIdx.x;
    int h = tid & 63, kg = tid >> 6;

    __shared__ float s_pw[K_];

    if (tid < K_) {
        float acc = 0.f;
        #pragma unroll
        for (int j = 0; j < CK_; ++j) {
            int ll = l - (CK_ - 1) + j;
            if (ll >= 0)
                acc += zmem[(size_t)(b*L_ + ll)*DMK + DIM_MEM_ + tid]
                     * conv_w[j*DMK + DIM_MEM_ + tid];
        }
        float s  = acc / (1.f + expf(-acc));
        float lp = sscale[tid] * s;
        lp = fminf(10.f, fmaxf(-10.f, lp));
        float slope = log1pf(expf(dslopes[tid]));
        s_pw[tid] = expf(lp - slope * (float)(L_ - 1 - l));
    }

    float kv[3];
    #pragma unroll
    for (int q = 0; q < 3; ++q) {
        int kk = kg + q*4;
        int c = kk*H_ + h;
        float acc = 0.f;
        #pragma unroll
        for (int j = 0; j < CK_; ++j) {
            int ll = l - (CK_ - 1) + j;
            if (ll >= 0)
                acc += zmem[(size_t)(b*L_ + ll)*DMK + c] * conv_w[j*DMK + c];
        }
        kv[q] = acc / (1.f + __expf(-acc));          // silu (hw exp)
    }
    __syncthreads();

    #pragma unroll
    for (int q = 0; q < 3; ++q) {
        int kk = kg + q*4;
        float v = kv[q];
        float ss = v * v;
        #pragma unroll
        for (int off = 32; off > 0; off >>= 1)
            ss += __shfl_xor(ss, off, 64);
        float kn = v * rsqrtf(ss * (1.f/64.f) + 1e-6f) * rms_scale[h];
        float th = 0.001f + 2.999f * (1.f / (1.f + __expf(-theta_raw[kk*H_ + h])));
        float phi = tanh_fast(kn * tscale[kk]) * th;
        float kvw = kn * s_pw[kk];
        re[(size_t)t*(K_*H_) + kk*H_ + h] = kvw * __cosf(phi);
        im[(size_t)t*(K_*H_) + kk*H_ + h] = kvw * __sinf(phi);
    }
    if (tid < K_) pw[(size_t)t*K_ + tid] = s_pw[tid];
}

// ---------------------------------------------------------------------------
// Chunked scan pass 1
// ---------------------------------------------------------------------------
__global__ __launch_bounds__(128)
void scan_sums(const float* __restrict__ pw, const float* __restrict__ re,
               const float* __restrict__ im, float* __restrict__ part)
{
    int blk = blockIdx.x;
    int chunk = blk & (NCHUNK - 1);
    int bk = blk >> 4;
    int k = bk % K_;
    int b = bk / K_;
    int tid = threadIdx.x;
    int h = tid & 63;
    const float* __restrict__ src = (tid >> 6) ? im : re;
    int l0 = chunk * CHLEN;

    size_t base  = ((size_t)(b*L_ + l0))*(K_*H_) + k*H_ + h;
    size_t dbase = ((size_t)(b*L_ + l0))*K_ + k;
    float s = 0.f, ds = 0.f;
    for (int i0 = 0; i0 < CHLEN; i0 += 8) {
        float v[8], d[8];
        #pragma unroll
        for (int j = 0; j < 8; ++j) {
            v[j] = src[base + (size_t)(i0 + j)*(K_*H_)];
            d[j] = pw [dbase + (size_t)(i0 + j)*K_];
        }
        #pragma unroll
        for (int j = 0; j < 8; ++j) { s += v[j]; ds += d[j]; }
    }
    size_t pb = ((size_t)bk * NCHUNK + chunk) * PSTRIDE;
    part[pb + tid] = s;
    if (tid == 0) part[pb + 128] = ds;
}

// ---------------------------------------------------------------------------
// Chunked scan pass 2: emit summary directly as bf16.
// ---------------------------------------------------------------------------
__global__ __launch_bounds__(128)
void scan_final(const float* __restrict__ pw, const float* __restrict__ re,
                const float* __restrict__ im, const float* __restrict__ part,
                ushort* __restrict__ summary)
{
    int blk = blockIdx.x;
    int chunk = blk & (NCHUNK - 1);
    int bk = blk >> 4;
    int k = bk % K_;
    int b = bk / K_;
    int tid = threadIdx.x;
    int h = tid & 63;
    int pi = tid >> 6;
    const float* __restrict__ src = pi ? im : re;
    int l0 = chunk * CHLEN;

    float acc = 0.f, dacc = 0.f;
    size_t pb0 = (size_t)bk * NCHUNK * PSTRIDE;
    for (int cn = 0; cn < chunk; ++cn) {
        acc  += part[pb0 + (size_t)cn*PSTRIDE + tid];
        dacc += part[pb0 + (size_t)cn*PSTRIDE + 128];
    }

    size_t base  = ((size_t)(b*L_ + l0))*(K_*H_) + k*H_ + h;
    size_t dbase = ((size_t)(b*L_ + l0))*K_ + k;
    int outch = 2*(k*H_ + h) + pi;
    for (int i0 = 0; i0 < CHLEN; i0 += 8) {
        float v[8], d[8];
        #pragma unroll
        for (int j = 0; j < 8; ++j) {
            v[j] = src[base + (size_t)(i0 + j)*(K_*H_)];
            d[j] = pw [dbase + (size_t)(i0 + j)*K_];
        }
        #pragma unroll
        for (int j = 0; j < 8; ++j) {
            acc += v[j]; dacc += d[j];
            float inv = 1.f / fmaxf(dacc, 1e-4f);
            summary[((size_t)(b*L_ + l0 + i0 + j))*NSUM + outch] = f2bf(acc * inv);
        }
    }
}

// ---------------------------------------------------------------------------
extern "C" void kernel_launch(void* const* d_in, const int* in_sizes, int n_in,
                              void* d_out, int out_size, void* d_ws, size_t ws_size,
                              hipStream_t stream)
{
    const float* x         = (const float*)d_in[0];
    const float* W_in      = (const float*)d_in[1];
    const float* conv_w    = (const float*)d_in[2];
    const float* rms_scale = (const float*)d_in[3];
    const float* theta_raw = (const float*)d_in[4];
    const float* dslopes   = (const float*)d_in[5];
    const float* sscale    = (const float*)d_in[6];
    const float* tscale    = (const float*)d_in[7];
    const float* W_sw      = (const float*)d_in[8];
    const float* W_out     = (const float*)d_in[9];
    float* out = (float*)d_out;
    char* ws   = (char*)d_ws;

    // Workspace (byte offsets, all 256-aligned). Peak ~115.4 MB (< proven 127).
    float*  zmem    = (float*) (ws + 0);           // NT*780 f32   = 25,559,040 B
    ushort* summary = (ushort*)(ws + 0);           // alias (zmem dead): 25,165,824 B
    float*  pw      = (float*) (ws + 25559040);    //   393,216 B
    float*  re      = (float*) (ws + 25952256);    // 25,165,824 B
    float*  im      = (float*) (ws + 51118080);    // 25,165,824 B
    ushort* yact    = (ushort*)(ws + 25952256);    // alias re+im (dead): 37,748,736 B
    float*  part    = (float*) (ws + 76283904);    //   405,504 B
    ushort* xb      = (ushort*)(ws + 76689408);    // 12,582,912 B
    ushort* WiCat   = (ushort*)(ws + 89272320);    //  7,077,888 B  [4608][768]  val/gate interleaved
    ushort* WsCat   = (ushort*)(ws + 96350208);    // 14,155,776 B  [4608][1536] val/gate interleaved
    ushort* WoT     = (ushort*)(ws + 110505984);   //  3,538,944 B  [768][2304]
    ushort* WimT    = (ushort*)(ws + 114044928);   //  1,376,256 B  [896][768] (pad)

    // ---- merged prep job table ----
    PrepJobs J{};
    J.W[0]=W_in;  J.out[0]=WiCat; J.ldw[0]=5388; J.Kd[0]=768;  J.colbase[0]=780; J.remap[0]=1; J.ntx[0]=144;
    J.W[1]=W_sw;  J.out[1]=WsCat; J.ldw[1]=4608; J.Kd[1]=1536; J.colbase[1]=0;   J.remap[1]=1; J.ntx[1]=144;
    J.W[2]=W_out; J.out[2]=WoT;   J.ldw[2]=768;  J.Kd[2]=2304; J.colbase[2]=0;   J.remap[2]=0; J.ntx[2]=24;
    J.W[3]=W_in;  J.out[3]=WimT;  J.ldw[3]=5388; J.Kd[3]=768;  J.colbase[3]=0;   J.remap[3]=0; J.ntx[3]=28;
    int tiles[4] = {144*24, 144*48, 24*72, 28*24};
    J.start[0] = 0;
    for (int j = 0; j < 4; ++j) J.start[j+1] = J.start[j] + tiles[j];
    J.start[5] = J.start[4];
    J.start[6] = J.start[4];
    J.cast_in = x; J.cast_out = xb; J.n4 = NT*D_/4;
    int nblk = J.start[6] + (J.n4 + 255)/256;

    dim3 blk(256);
    // 0) all preps in one launch
    prep_all<<<dim3(nblk), blk, 0, stream>>>(J);
    // 1) z_mem = x @ W_in[:, :780]  (bf16 MFMA, col-guarded at 780)
    gemm_bf16_mfma<<<dim3(7, 64), blk, 0, stream>>>(xb, WimT, zmem, 768, 780, 780);
    // 2) conv + silu + rmsnorm + phase
    token_kernel<<<dim3(NT), blk, 0, stream>>>(zmem, conv_w, rms_scale, theta_raw,
                                               dslopes, sscale, tscale, pw, re, im);
    // 3) chunked cumsum -> summary (bf16)
    scan_sums <<<dim3(B_*K_*NCHUNK), dim3(128), 0, stream>>>(pw, re, im, part);
    scan_final<<<dim3(B_*K_*NCHUNK), dim3(128), 0, stream>>>(pw, re, im, part, summary);
    // 4) fused spectral+skip pipelined GEMM, 2 blocks/CU -> yact (bf16)
    gemm2_2blk<<<dim3(24, 64), dim3(256), 0, stream>>>(summary, xb, WsCat, WiCat, yact);
    // 5) out = yact @ W_out  (MFMA)
    gemm_bf16_mfma<<<dim3(6, 64), blk, 0, stream>>>(yact, WoT, out, 2304, 768, 768);
}